// Round 4
// baseline (39.504 us; speedup 1.0000x reference)
//
#include <hip/hip_runtime.h>
#include <math.h>

// Problem constants (from reference)
#define BB 16
#define CC 3
#define OO 32
#define HH 128
#define WW 128
#define OH 124
#define OW 124
#define NPIX (OH * OW)          // 15376
#define NG   (NPIX / 4)         // 3844 4-pixel groups
#define GW   (OW / 4)           // 31 groups per output row
#define KF 25.0f

#define OG2  4                  // o-groups in partial kernel (8 o's each)
#define OPT2 8
#define OG4  8                  // o-groups in final kernel (4 o's each)
#define OPT4 4

#if defined(__has_builtin)
#if __has_builtin(__builtin_amdgcn_sqrtf)
#define FSQRT(x) __builtin_amdgcn_sqrtf(x)
#else
#define FSQRT(x) sqrtf(x)
#endif
#else
#define FSQRT(x) sqrtf(x)
#endif

// ---------------------------------------------------------------------------
// Kernel 1: window sums. Thread per (b, c, 4-pixel group).
// 10 float4 row loads, rolling 5-wide window, 2 float4 stores.
// ---------------------------------------------------------------------------
__global__ void win_sums4(const float* __restrict__ x,
                          float* __restrict__ s1,
                          float* __restrict__ s2) {
    int idx = blockIdx.x * blockDim.x + threadIdx.x;
    if (idx >= BB * CC * NG) return;
    int g  = idx % NG;
    int bc = idx / NG;
    int i  = g / GW;
    int j0 = (g % GW) * 4;
    int pixb = i * OW + j0;

    const float* img = x + (size_t)bc * (HH * WW);
    float S1[4] = {0, 0, 0, 0}, S2[4] = {0, 0, 0, 0};
#pragma unroll
    for (int di = 0; di < 5; ++di) {
        const float4* rp = reinterpret_cast<const float4*>(img + (i + di) * WW + j0);
        float4 lo = rp[0], hi = rp[1];
        float v[8] = {lo.x, lo.y, lo.z, lo.w, hi.x, hi.y, hi.z, hi.w};
        float q[8];
#pragma unroll
        for (int k = 0; k < 8; ++k) q[k] = v[k] * v[k];
        float r  = v[0] + v[1] + v[2] + v[3] + v[4];
        float rq = q[0] + q[1] + q[2] + q[3] + q[4];
        S1[0] += r;  S2[0] += rq;
#pragma unroll
        for (int t = 1; t < 4; ++t) {
            r  += v[t + 4] - v[t - 1];
            rq += q[t + 4] - q[t - 1];
            S1[t] += r;  S2[t] += rq;
        }
    }
    float4 a  = {S1[0], S1[1], S1[2], S1[3]};
    float4 qq = {S2[0], S2[1], S2[2], S2[3]};
    *reinterpret_cast<float4*>(&s1[(size_t)bc * NPIX + pixb]) = a;
    *reinterpret_cast<float4*>(&s2[(size_t)bc * NPIX + pixb]) = qq;
}

// ---------------------------------------------------------------------------
// Kernel 2: partial o-reduction. Thread per (b, o-octet, 4-pixel group).
// psum/psq layout [(b*OG2+og)*NPIX + pix].
// ---------------------------------------------------------------------------
__global__ void partial8(const float* __restrict__ s1,
                         const float* __restrict__ s2,
                         const float* __restrict__ wgt,
                         float* __restrict__ psum,
                         float* __restrict__ psq) {
    int idx = blockIdx.x * blockDim.x + threadIdx.x;
    if (idx >= BB * OG2 * NG) return;
    int g  = idx % NG;
    int r_ = idx / NG;
    int og = r_ % OG2;
    int b  = r_ / OG2;
    int i  = g / GW;
    int j0 = (g % GW) * 4;
    int pixb = i * OW + j0;

    float S1c[CC][4], S2c[CC][4];
#pragma unroll
    for (int c = 0; c < CC; ++c) {
        float4 a = *reinterpret_cast<const float4*>(&s1[(size_t)(b * CC + c) * NPIX + pixb]);
        float4 q = *reinterpret_cast<const float4*>(&s2[(size_t)(b * CC + c) * NPIX + pixb]);
        S1c[c][0] = a.x; S1c[c][1] = a.y; S1c[c][2] = a.z; S1c[c][3] = a.w;
        S2c[c][0] = q.x; S2c[c][1] = q.y; S2c[c][2] = q.z; S2c[c][3] = q.w;
    }

    float sum[4] = {0, 0, 0, 0}, sq[4] = {0, 0, 0, 0};
#pragma unroll
    for (int oo = 0; oo < OPT2; ++oo) {
        int o = og * OPT2 + oo;
        float d[4] = {0, 0, 0, 0};
#pragma unroll
        for (int c = 0; c < CC; ++c) {
            float w  = wgt[o * CC + c];      // uniform -> scalar load
            float tw = 2.0f * w;
            float kw = KF * w * w;
#pragma unroll
            for (int t = 0; t < 4; ++t) {
                float inner = S2c[c][t] - tw * S1c[c][t] + kw;
                d[t] += FSQRT(fmaxf(inner, 0.0f));
            }
        }
#pragma unroll
        for (int t = 0; t < 4; ++t) { sum[t] += d[t]; sq[t] += d[t] * d[t]; }
    }
    float4 fs = {sum[0], sum[1], sum[2], sum[3]};
    float4 fq = {sq[0], sq[1], sq[2], sq[3]};
    *reinterpret_cast<float4*>(&psum[(size_t)(b * OG2 + og) * NPIX + pixb]) = fs;
    *reinterpret_cast<float4*>(&psq [(size_t)(b * OG2 + og) * NPIX + pixb]) = fq;
}

// ---------------------------------------------------------------------------
// Kernel 3: per-pixel 1/std over the 64 (b,og) partials (double acc).
// Thread per pixel; loads coalesced across threads.
// ---------------------------------------------------------------------------
__global__ void inv_std_kernel(const float* __restrict__ psum,
                               const float* __restrict__ psq,
                               float* __restrict__ invstd) {
    int pix = blockIdx.x * blockDim.x + threadIdx.x;
    if (pix >= NPIX) return;
    double sm = 0.0, sQ = 0.0;
#pragma unroll 8
    for (int r = 0; r < BB * OG2; ++r) {
        sm += (double)psum[(size_t)r * NPIX + pix];
        sQ += (double)psq [(size_t)r * NPIX + pix];
    }
    const double n = (double)(BB * OO);
    double mean = sm / n;
    double var = (sQ - n * mean * mean) / (n - 1.0);
    if (var < 0.0) var = 0.0;
    invstd[pix] = (float)(1.0 / sqrt(var));
}

// ---------------------------------------------------------------------------
// Kernel 4: final output. Thread per (b, o-quad, 4-pixel group).
// 7 float4 L2-hit loads, 48 sqrt + 16 exp, 4 coalesced float4 stores.
// ---------------------------------------------------------------------------
__global__ void final4(const float* __restrict__ s1,
                       const float* __restrict__ s2,
                       const float* __restrict__ wgt,
                       const float* __restrict__ invstd,
                       float* __restrict__ out) {
    int idx = blockIdx.x * blockDim.x + threadIdx.x;
    if (idx >= BB * OG4 * NG) return;
    int g  = idx % NG;
    int r_ = idx / NG;
    int og = r_ % OG4;
    int b  = r_ / OG4;
    int i  = g / GW;
    int j0 = (g % GW) * 4;
    int pixb = i * OW + j0;

    float S1c[CC][4], S2c[CC][4];
#pragma unroll
    for (int c = 0; c < CC; ++c) {
        float4 a = *reinterpret_cast<const float4*>(&s1[(size_t)(b * CC + c) * NPIX + pixb]);
        float4 q = *reinterpret_cast<const float4*>(&s2[(size_t)(b * CC + c) * NPIX + pixb]);
        S1c[c][0] = a.x; S1c[c][1] = a.y; S1c[c][2] = a.z; S1c[c][3] = a.w;
        S2c[c][0] = q.x; S2c[c][1] = q.y; S2c[c][2] = q.z; S2c[c][3] = q.w;
    }
    float4 iv = *reinterpret_cast<const float4*>(&invstd[pixb]);
    float isd[4] = {iv.x, iv.y, iv.z, iv.w};

#pragma unroll
    for (int oo = 0; oo < OPT4; ++oo) {
        int o = og * OPT4 + oo;
        float d[4] = {0, 0, 0, 0};
#pragma unroll
        for (int c = 0; c < CC; ++c) {
            float w  = wgt[o * CC + c];
            float tw = 2.0f * w;
            float kw = KF * w * w;
#pragma unroll
            for (int t = 0; t < 4; ++t) {
                float inner = S2c[c][t] - tw * S1c[c][t] + kw;
                d[t] += FSQRT(fmaxf(inner, 0.0f));
            }
        }
        float4 r;
        float z0 = d[0] * isd[0]; r.x = __expf(-0.5f * z0 * z0);
        float z1 = d[1] * isd[1]; r.y = __expf(-0.5f * z1 * z1);
        float z2 = d[2] * isd[2]; r.z = __expf(-0.5f * z2 * z2);
        float z3 = d[3] * isd[3]; r.w = __expf(-0.5f * z3 * z3);
        *reinterpret_cast<float4*>(&out[(size_t)(b * OO + o) * NPIX + pixb]) = r;
    }
}

// ---------------------------------------------------------------------------
extern "C" void kernel_launch(void* const* d_in, const int* in_sizes, int n_in,
                              void* d_out, int out_size, void* d_ws, size_t ws_size,
                              hipStream_t stream) {
    const float* x   = (const float*)d_in[0];   // (16,3,128,128)
    const float* wgt = (const float*)d_in[1];   // (32,3)
    float* out = (float*)d_out;                 // (16,32,124,124)

    // Workspace (floats): s1 [B*C*NPIX] | s2 [B*C*NPIX] |
    //                     psum [B*OG2*NPIX] | psq [B*OG2*NPIX] | invstd [NPIX]
    float* s1     = (float*)d_ws;
    float* s2     = s1 + (size_t)BB * CC * NPIX;
    float* psum   = s2 + (size_t)BB * CC * NPIX;
    float* psq    = psum + (size_t)BB * OG2 * NPIX;
    float* invstd = psq + (size_t)BB * OG2 * NPIX;

    const int block = 256;
    {
        int total = BB * CC * NG;                 // 184,512
        win_sums4<<<(total + block - 1) / block, block, 0, stream>>>(x, s1, s2);
    }
    {
        int total = BB * OG2 * NG;                // 246,016
        partial8<<<(total + block - 1) / block, block, 0, stream>>>(s1, s2, wgt, psum, psq);
    }
    {
        inv_std_kernel<<<(NPIX + block - 1) / block, block, 0, stream>>>(psum, psq, invstd);
    }
    {
        int total = BB * OG4 * NG;                // 492,032
        final4<<<(total + block - 1) / block, block, 0, stream>>>(s1, s2, wgt, invstd, out);
    }
}